// Round 11
// baseline (253.318 us; speedup 1.0000x reference)
//
#include <hip/hip_runtime.h>
#include <math.h>

// Problem constants: D=64 dialogues, L=64, DIM=512, G=256
// m = 3*L = 192 nodes/hyperedges per dialogue, k = 12, N = D*L = 4096
#define NDIAL 64
#define M3    192
#define DIMF  512
#define GDIM  256
#define NROW  4096
#define TOPK  12
#define INV_TAU (1.0f/0.07f)

typedef __attribute__((ext_vector_type(8))) short bf16x8;
typedef __attribute__((ext_vector_type(4))) float f32x4;
typedef __attribute__((ext_vector_type(8))) ushort us8;
typedef _Float16 f16x8 __attribute__((ext_vector_type(8)));
typedef _Float16 f16x4v __attribute__((ext_vector_type(4)));
typedef __attribute__((address_space(3))) ushort lds_us;
typedef const __attribute__((address_space(1))) ushort gm_us;

__device__ __forceinline__ ushort f2bf(float f) {
    unsigned u = __float_as_uint(f);
    unsigned r = (u + 0x7fff + ((u >> 16) & 1)) >> 16;   // RNE
    return (ushort)r;
}

__device__ __forceinline__ const float* node_ptr(const float* t, const float* a,
                                                 const float* v, int d, int j) {
    int mod = j >> 6, i = j & 63;
    const float* base = (mod == 0) ? t : (mod == 1) ? a : v;
    return base + (size_t)(d * 64 + i) * DIMF;
}

// 8 fp32 -> hi/lo fp16 split (RNE; identical formulas to the old kprep path,
// so MFMA inputs -- and therefore d2 -- are bit-identical)
__device__ __forceinline__ void cvt_hilo(const float* __restrict__ src,
                                         f16x8* h, f16x8* l) {
    float4 x0 = *(const float4*)src;
    float4 x1 = *(const float4*)(src + 4);
    f16x8 hh, ll;
    hh[0] = (_Float16)x0.x; ll[0] = (_Float16)(x0.x - (float)hh[0]);
    hh[1] = (_Float16)x0.y; ll[1] = (_Float16)(x0.y - (float)hh[1]);
    hh[2] = (_Float16)x0.z; ll[2] = (_Float16)(x0.z - (float)hh[2]);
    hh[3] = (_Float16)x0.w; ll[3] = (_Float16)(x0.w - (float)hh[3]);
    hh[4] = (_Float16)x1.x; ll[4] = (_Float16)(x1.x - (float)hh[4]);
    hh[5] = (_Float16)x1.y; ll[5] = (_Float16)(x1.y - (float)hh[5]);
    hh[6] = (_Float16)x1.z; ll[6] = (_Float16)(x1.z - (float)hh[6]);
    hh[7] = (_Float16)x1.w; ll[7] = (_Float16)(x1.w - (float)hh[7]);
    *h = hh; *l = ll;
}

// 8 fp32 -> fp16 (RNE, identical to old kprep featb conversion)
__device__ __forceinline__ f16x8 cvt_hi(const float* __restrict__ src) {
    float4 x0 = *(const float4*)src;
    float4 x1 = *(const float4*)(src + 4);
    f16x8 hh;
    hh[0] = (_Float16)x0.x; hh[1] = (_Float16)x0.y;
    hh[2] = (_Float16)x0.z; hh[3] = (_Float16)x0.w;
    hh[4] = (_Float16)x1.x; hh[5] = (_Float16)x1.y;
    hh[6] = (_Float16)x1.z; hh[7] = (_Float16)x1.w;
    return hh;
}

// ---- KA: merged kprep + k1.
//      Blocks 0..383: k1 tiles -- split-f16 MFMA distances, fp32 inputs
//        converted inline (bit-identical to the old featb/featlo path).
//        Stores s = 2*dot (EXACT; sq/clamp deferred to k2 -- the expression
//        k2 computes is the same fp tree, so top-k input is bit-identical).
//        No dependency on prep blocks -> race-free in one launch.
//      Blocks 384+: prep -- sq norms (EXACT R10 code/order: frozen numeric
//        path), WfcT/WhT transposes, zero-inits. ----
__global__ __launch_bounds__(256) void kA(const float* __restrict__ t,
                      const float* __restrict__ a, const float* __restrict__ v,
                      const float* __restrict__ Wfc, const float* __restrict__ Wh,
                      _Float16* __restrict__ WfcT, _Float16* __restrict__ WhT,
                      float* __restrict__ sq, float* __restrict__ rs,
                      float* __restrict__ cs, float* __restrict__ degV,
                      _Float16* __restrict__ HbT, float* __restrict__ d2) {
    __shared__ __align__(16) _Float16 Ahs[64 * 40], Als[64 * 40];
    __shared__ __align__(16) _Float16 Bhs[64 * 40], Bls[64 * 40];
    __shared__ float part[4];
    int b = blockIdx.x, tid = threadIdx.x;

    if (b < 384) {
        // ---------------- k1 tile block ----------------
        int tileid = b % 6;                  // 0..5 upper triangle
        int d = b / 6;
        int bi = (tileid < 3) ? 0 : (tileid < 5) ? 1 : 2;
        int bj = (tileid < 3) ? tileid : (tileid < 5) ? tileid - 2 : 2;
        const float* Abase = ((bi == 0) ? t : (bi == 1) ? a : v) + (size_t)d * 64 * DIMF;
        const float* Bbase = ((bj == 0) ? t : (bj == 1) ? a : v) + (size_t)d * 64 * DIMF;

        const int lane = tid & 63, w = tid >> 6;     // 4 waves
        const int qd = lane >> 4, l15 = lane & 15;

        f32x4 acc[4];                                // fm = 0..3, fn = w
#pragma unroll
        for (int fm = 0; fm < 4; fm++) acc[fm] = (f32x4){0.f, 0.f, 0.f, 0.f};

        const int row = tid >> 2, c8 = tid & 3;      // 256 thr cover 64x32
        for (int k0 = 0; k0 < DIMF; k0 += 32) {
            f16x8 h, l;
            cvt_hilo(&Abase[(size_t)row * DIMF + k0 + c8 * 8], &h, &l);
            *(f16x8*)&Ahs[row * 40 + c8 * 8] = h;
            *(f16x8*)&Als[row * 40 + c8 * 8] = l;
            cvt_hilo(&Bbase[(size_t)row * DIMF + k0 + c8 * 8], &h, &l);
            *(f16x8*)&Bhs[row * 40 + c8 * 8] = h;
            *(f16x8*)&Bls[row * 40 + c8 * 8] = l;
            __syncthreads();
            f16x8 bh = *(const f16x8*)&Bhs[(w * 16 + l15) * 40 + qd * 8];
            f16x8 bl = *(const f16x8*)&Bls[(w * 16 + l15) * 40 + qd * 8];
#pragma unroll
            for (int fm = 0; fm < 4; fm++) {
                f16x8 ah = *(const f16x8*)&Ahs[(fm * 16 + l15) * 40 + qd * 8];
                f16x8 al = *(const f16x8*)&Als[(fm * 16 + l15) * 40 + qd * 8];
                acc[fm] = __builtin_amdgcn_mfma_f32_16x16x32_f16(ah, bh, acc[fm], 0, 0, 0);
                acc[fm] = __builtin_amdgcn_mfma_f32_16x16x32_f16(ah, bl, acc[fm], 0, 0, 0);
                acc[fm] = __builtin_amdgcn_mfma_f32_16x16x32_f16(al, bh, acc[fm], 0, 0, 0);
                acc[fm] = __builtin_amdgcn_mfma_f32_16x16x32_f16(al, bl, acc[fm], 0, 0, 0);
            }
            __syncthreads();
        }

        float* outp = d2 + (size_t)d * M3 * M3;
#pragma unroll
        for (int fm = 0; fm < 4; fm++)
#pragma unroll
            for (int rg = 0; rg < 4; rg++) {
                int il = bi * 64 + fm * 16 + qd * 4 + rg;
                int jl = bj * 64 + w * 16 + l15;
                float s = 2.f * acc[fm][rg];         // exact; clamp+sq in k2
                outp[(size_t)il * M3 + jl] = s;
                if (bi != bj) outp[(size_t)jl * M3 + il] = s;
            }
    } else if (b < 6528) {
        // ---------------- sq norms (EXACT R10 code path) ----------------
        int bb = b - 384;
        int e = (bb * 256 + tid) * 4;
        int d = e / (M3 * DIMF);
        int rem = e % (M3 * DIMF);
        int n = rem / DIMF, kk = rem % DIMF;
        int mod = n >> 6, i = n & 63;
        const float* src = ((mod == 0) ? t : (mod == 1) ? a : v)
                           + (size_t)(d * 64 + i) * DIMF + kk;
        float4 x = *(const float4*)src;
        float s = x.x * x.x + x.y * x.y + x.z * x.z + x.w * x.w;
#pragma unroll
        for (int o2 = 32; o2; o2 >>= 1) s += __shfl_down(s, o2);
        int wv = tid >> 6;
        if ((tid & 63) == 0) part[wv] = s;
        __syncthreads();
        if (tid < 2) sq[2 * bb + tid] = part[2 * tid] + part[2 * tid + 1];
    } else if (b < 6656) {
        int e = ((b - 6528) * 256 + tid) * 4;
        int g = e >> 9, kk = e & 511;
        f16x4v o = {(_Float16)Wfc[(size_t)(kk + 0) * GDIM + g],
                    (_Float16)Wfc[(size_t)(kk + 1) * GDIM + g],
                    (_Float16)Wfc[(size_t)(kk + 2) * GDIM + g],
                    (_Float16)Wfc[(size_t)(kk + 3) * GDIM + g]};
        *(f16x4v*)&WfcT[(size_t)g * DIMF + kk] = o;
    } else if (b < 6720) {
        int e = ((b - 6656) * 256 + tid) * 4;
        int go = e >> 8, g = e & 255;
        f16x4v o = {(_Float16)Wh[(size_t)(g + 0) * GDIM + go],
                    (_Float16)Wh[(size_t)(g + 1) * GDIM + go],
                    (_Float16)Wh[(size_t)(g + 2) * GDIM + go],
                    (_Float16)Wh[(size_t)(g + 3) * GDIM + go]};
        *(f16x4v*)&WhT[(size_t)go * GDIM + g] = o;
    } else if (b < 6768) {
        int i = (b - 6720) * 256 + tid;
        rs[i] = 0.f; cs[i] = 0.f; degV[i] = 0.f;
    } else {
        int i = (b - 6768) * 256 + tid;
        ulonglong2 z = {0ull, 0ull};
        *(ulonglong2*)&HbT[(size_t)i * 8] = z;
    }
}

// ---- K2: wave-per-row top-12 + fp16 H build + HbT scatter + degrees.
//      R11: reconstructs clamped d2 from s = 2*dot + sq (bit-identical fp
//      tree to the old k1 epilogue: (sqe + qj) - s, fmax 0; add commutes). ----
__global__ void k2_topk(const float* __restrict__ d2, const float* __restrict__ sq,
                        _Float16* __restrict__ Hb,
                        _Float16* __restrict__ HbT, float* __restrict__ degE,
                        float* __restrict__ degV) {
    int lane = threadIdx.x & 63, wv = threadIdx.x >> 6;
    int r = blockIdx.x * 4 + wv;                 // 0..12287
    int d = r / M3, e = r % M3;
    const float* row = d2 + (size_t)r * M3;
    const float* sqd = sq + d * M3;
    float sqe = sqd[e];
    float w0 = fmaxf(sqe + sqd[lane]       - row[lane],       0.f);
    float w1 = fmaxf(sqe + sqd[lane + 64]  - row[lane + 64],  0.f);
    float w2 = fmaxf(sqe + sqd[lane + 128] - row[lane + 128], 0.f);
    bool s0 = false, s1 = false, s2 = false;
#pragma unroll
    for (int it = 0; it < TOPK; it++) {
        float bv = w0; int bi = lane;
        if (w1 < bv) { bv = w1; bi = lane + 64; }
        if (w2 < bv) { bv = w2; bi = lane + 128; }
#pragma unroll
        for (int o = 1; o < 64; o <<= 1) {
            float ov = __shfl_xor(bv, o);
            int   oi = __shfl_xor(bi, o);
            if (ov < bv || (ov == bv && oi < bi)) { bv = ov; bi = oi; }
        }
        if (bi == lane)            { s0 = true; w0 = 3.4e38f; }
        else if (bi == lane + 64)  { s1 = true; w1 = 3.4e38f; }
        else if (bi == lane + 128) { s2 = true; w2 = 3.4e38f; }
    }
    int u = e / 3;
    if (lane == u) { s0 = true; s1 = true; s2 = true; }
    float f0 = s0 ? 1.f : 0.f, f1 = s1 ? 1.f : 0.f, f2 = s2 ? 1.f : 0.f;
    _Float16* Hrow = Hb + (size_t)r * M3;
    Hrow[lane] = (_Float16)f0;
    Hrow[lane + 64] = (_Float16)f1;
    Hrow[lane + 128] = (_Float16)f2;
    float cnt = f0 + f1 + f2;
#pragma unroll
    for (int o = 1; o < 64; o <<= 1) cnt += __shfl_xor(cnt, o);
    if (lane == 0) degE[r] = cnt;
    float* dv = degV + d * M3;
    _Float16* HT = HbT + (size_t)d * M3 * M3;
    if (s0) { atomicAdd(&dv[lane], 1.f);       HT[(size_t)lane * M3 + e] = (_Float16)1.f; }
    if (s1) { atomicAdd(&dv[lane + 64], 1.f);  HT[(size_t)(lane + 64) * M3 + e] = (_Float16)1.f; }
    if (s2) { atomicAdd(&dv[lane + 128], 1.f); HT[(size_t)(lane + 128) * M3 + e] = (_Float16)1.f; }
}

// ---- K34: fused k3+k4, 32 g-rows/block, grid (8,64). R11: B operand
//      converted inline from fp32 t/a/v (identical RNE -> X bit-identical);
//      featb is dead. ----
__global__ __launch_bounds__(192) void k34_XE(const _Float16* __restrict__ WfcT,
                      const float* __restrict__ t, const float* __restrict__ a,
                      const float* __restrict__ v,
                      const float* __restrict__ bfc,
                      const _Float16* __restrict__ Hb,
                      const float* __restrict__ degE,
                      _Float16* __restrict__ ET) {
    int gb = blockIdx.x, d = blockIdx.y;         // grid (8,64); 32 g-rows
    const _Float16* A = WfcT + (size_t)gb * 32 * DIMF;     // 32 x 512
    const _Float16* H = Hb + (size_t)d * M3 * M3;          // 192 x 192

    __shared__ __align__(16) _Float16 As[32 * 40];
    __shared__ __align__(16) _Float16 Bs[M3 * 40];
    __shared__ __align__(16) _Float16 Xls[32 * 200];       // XT rows, fp16
    const int tid = threadIdx.x;
    const int lane = tid & 63, w = tid >> 6;     // 3 waves (col strips)
    const int qd = lane >> 4, l15 = lane & 15;

    f32x4 acc[2][4];
#pragma unroll
    for (int fm = 0; fm < 2; fm++)
#pragma unroll
        for (int fn = 0; fn < 4; fn++) acc[fm][fn] = (f32x4){0.f, 0.f, 0.f, 0.f};

    // ---- phase 1: XTrows = A (32x512) @ feat^T (K = 512), feat inline ----
    for (int k0 = 0; k0 < DIMF; k0 += 32) {
        if (tid < 128) {
            int row = tid >> 2, c8 = tid & 3;
            *(float4*)&As[row * 40 + c8 * 8] =
                *(const float4*)&A[(size_t)row * DIMF + k0 + c8 * 8];
        }
#pragma unroll
        for (int i = 0; i < 4; i++) {
            int f = tid + i * 192;
            int row = f >> 2, c8 = f & 3;
            const float* src = node_ptr(t, a, v, d, row) + k0 + c8 * 8;
            *(f16x8*)&Bs[row * 40 + c8 * 8] = cvt_hi(src);
        }
        __syncthreads();
        f16x8 af[2], bfr[4];
#pragma unroll
        for (int fm = 0; fm < 2; fm++)
            af[fm] = *(const f16x8*)&As[(fm * 16 + l15) * 40 + qd * 8];
#pragma unroll
        for (int fn = 0; fn < 4; fn++)
            bfr[fn] = *(const f16x8*)&Bs[(w * 64 + fn * 16 + l15) * 40 + qd * 8];
#pragma unroll
        for (int fm = 0; fm < 2; fm++)
#pragma unroll
            for (int fn = 0; fn < 4; fn++)
                acc[fm][fn] = __builtin_amdgcn_mfma_f32_16x16x32_f16(
                    af[fm], bfr[fn], acc[fm][fn], 0, 0, 0);
        __syncthreads();
    }
    // write XT rows (+bias, fp16) to Xls; row = g-local, col = n
#pragma unroll
    for (int fm = 0; fm < 2; fm++)
#pragma unroll
        for (int rg = 0; rg < 4; rg++) {
            int row = fm * 16 + qd * 4 + rg;
            float bias = bfc[gb * 32 + row];
#pragma unroll
            for (int fn = 0; fn < 4; fn++) {
                int col = w * 64 + fn * 16 + l15;
                Xls[row * 200 + col] = (_Float16)(acc[fm][fn][rg] + bias);
            }
        }
    __syncthreads();

    // ---- phase 2: ETrows = Xls (32x192) @ H^T (K = 192) ----
#pragma unroll
    for (int fm = 0; fm < 2; fm++)
#pragma unroll
        for (int fn = 0; fn < 4; fn++) acc[fm][fn] = (f32x4){0.f, 0.f, 0.f, 0.f};
    for (int k0 = 0; k0 < M3; k0 += 32) {
#pragma unroll
        for (int i = 0; i < 4; i++) {
            int f = tid + i * 192;
            int row = f >> 2, c8 = f & 3;
            *(float4*)&Bs[row * 40 + c8 * 8] =
                *(const float4*)&H[(size_t)row * M3 + k0 + c8 * 8];
        }
        __syncthreads();
        f16x8 af[2], bfr[4];
#pragma unroll
        for (int fm = 0; fm < 2; fm++)
            af[fm] = *(const f16x8*)&Xls[(fm * 16 + l15) * 200 + k0 + qd * 8];
#pragma unroll
        for (int fn = 0; fn < 4; fn++)
            bfr[fn] = *(const f16x8*)&Bs[(w * 64 + fn * 16 + l15) * 40 + qd * 8];
#pragma unroll
        for (int fm = 0; fm < 2; fm++)
#pragma unroll
            for (int fn = 0; fn < 4; fn++)
                acc[fm][fn] = __builtin_amdgcn_mfma_f32_16x16x32_f16(
                    af[fm], bfr[fn], acc[fm][fn], 0, 0, 0);
        __syncthreads();
    }
    float ide[4];
#pragma unroll
    for (int fn = 0; fn < 4; fn++)
        ide[fn] = 1.f / degE[d * M3 + w * 64 + fn * 16 + l15];
    _Float16* out = ET + (size_t)d * GDIM * M3;
#pragma unroll
    for (int fm = 0; fm < 2; fm++)
#pragma unroll
        for (int rg = 0; rg < 4; rg++) {
            int g = gb * 32 + fm * 16 + qd * 4 + rg;
#pragma unroll
            for (int fn = 0; fn < 4; fn++) {
                int e = w * 64 + fn * 16 + l15;
                out[(size_t)g * M3 + e] = (_Float16)(acc[fm][fn][rg] * ide[fn]);
            }
        }
}

// ---- K56: fused k5+k6, 32 nodes/block, grid (6,64) (R10, verified). ----
__global__ __launch_bounds__(256) void k56_Yout(const _Float16* __restrict__ HbT,
                      const _Float16* __restrict__ ET,
                      const float* __restrict__ degV,
                      const _Float16* __restrict__ WhT,
                      const float* __restrict__ bh,
                      float* __restrict__ outp,
                      ushort* __restrict__ xnb) {
    int nb = blockIdx.x, d = blockIdx.y;         // grid (6,64)
    int mod = nb >> 1, half = nb & 1;
    const int nlo = mod * 64 + half * 32;        // first node of band
    const _Float16* A = HbT + (size_t)d * M3 * M3 + (size_t)nlo * M3;  // 32x192
    const _Float16* B = ET + (size_t)d * GDIM * M3;                    // 256x192

    __shared__ __align__(16) _Float16 As[32 * 40];
    __shared__ __align__(16) _Float16 Bs[GDIM * 40];     // phase1 B & phase2 WhT
    __shared__ __align__(16) _Float16 Yls[32 * 264];     // Y band, fp16
    __shared__ float tile[32 * 256];
    __shared__ float ssq[32];
    const int tid = threadIdx.x;
    const int lane = tid & 63, w = tid >> 6;     // 4 waves (col strips)
    const int qd = lane >> 4, l15 = lane & 15;
    if (tid < 32) ssq[tid] = 0.f;

    f32x4 acc[2][4];
#pragma unroll
    for (int fm = 0; fm < 2; fm++)
#pragma unroll
        for (int fn = 0; fn < 4; fn++) acc[fm][fn] = (f32x4){0.f, 0.f, 0.f, 0.f};

    // ---- phase 1 (k5): Y = A (32x192) @ B^T, K = 192 ----
    for (int k0 = 0; k0 < M3; k0 += 32) {
        if (tid < 128) {
            int row = tid >> 2, c8 = tid & 3;
            *(float4*)&As[row * 40 + c8 * 8] =
                *(const float4*)&A[(size_t)row * M3 + k0 + c8 * 8];
        }
#pragma unroll
        for (int i = 0; i < 4; i++) {
            int f = tid + i * 256;
            int row = f >> 2, c8 = f & 3;
            *(float4*)&Bs[row * 40 + c8 * 8] =
                *(const float4*)&B[(size_t)row * M3 + k0 + c8 * 8];
        }
        __syncthreads();
        f16x8 af[2], bfr[4];
#pragma unroll
        for (int fm = 0; fm < 2; fm++)
            af[fm] = *(const f16x8*)&As[(fm * 16 + l15) * 40 + qd * 8];
#pragma unroll
        for (int fn = 0; fn < 4; fn++)
            bfr[fn] = *(const f16x8*)&Bs[(w * 64 + fn * 16 + l15) * 40 + qd * 8];
#pragma unroll
        for (int fm = 0; fm < 2; fm++)
#pragma unroll
            for (int fn = 0; fn < 4; fn++)
                acc[fm][fn] = __builtin_amdgcn_mfma_f32_16x16x32_f16(
                    af[fm], bfr[fn], acc[fm][fn], 0, 0, 0);
        __syncthreads();
    }
    // write Y band (/degV, fp16) to Yls; row = node-local ml, col = g
#pragma unroll
    for (int fm = 0; fm < 2; fm++)
#pragma unroll
        for (int rg = 0; rg < 4; rg++) {
            int ml = fm * 16 + qd * 4 + rg;
            float idv = 1.f / degV[d * M3 + nlo + ml];
#pragma unroll
            for (int fn = 0; fn < 4; fn++) {
                int g = w * 64 + fn * 16 + l15;
                Yls[ml * 264 + g] = (_Float16)(acc[fm][fn][rg] * idv);
            }
        }
    __syncthreads();

    // ---- phase 2 (k6): out = Yls (32x256) @ WhT^T, K = 256 ----
#pragma unroll
    for (int fm = 0; fm < 2; fm++)
#pragma unroll
        for (int fn = 0; fn < 4; fn++) acc[fm][fn] = (f32x4){0.f, 0.f, 0.f, 0.f};
    for (int k0 = 0; k0 < GDIM; k0 += 32) {
#pragma unroll
        for (int i = 0; i < 4; i++) {
            int f = tid + i * 256;
            int row = f >> 2, c8 = f & 3;
            *(float4*)&Bs[row * 40 + c8 * 8] =
                *(const float4*)&WhT[(size_t)row * GDIM + k0 + c8 * 8];
        }
        __syncthreads();
        f16x8 af[2], bfr[4];
#pragma unroll
        for (int fm = 0; fm < 2; fm++)
            af[fm] = *(const f16x8*)&Yls[(fm * 16 + l15) * 264 + k0 + qd * 8];
#pragma unroll
        for (int fn = 0; fn < 4; fn++)
            bfr[fn] = *(const f16x8*)&Bs[(w * 64 + fn * 16 + l15) * 40 + qd * 8];
#pragma unroll
        for (int fm = 0; fm < 2; fm++)
#pragma unroll
            for (int fn = 0; fn < 4; fn++)
                acc[fm][fn] = __builtin_amdgcn_mfma_f32_16x16x32_f16(
                    af[fm], bfr[fn], acc[fm][fn], 0, 0, 0);
        __syncthreads();
    }

    // ---- epilogue: bias+relu -> fp32 out, row-normalize -> swizzled xnb ----
    float bb[4];
#pragma unroll
    for (int fn = 0; fn < 4; fn++)
        bb[fn] = bh[w * 64 + fn * 16 + l15];
#pragma unroll
    for (int fm = 0; fm < 2; fm++)
#pragma unroll
        for (int rg = 0; rg < 4; rg++) {
            int i = fm * 16 + qd * 4 + rg;       // row within 32-row band
            float* orow = outp + (size_t)(d * 64 + half * 32 + i) * 768 + mod * GDIM;
            float s2 = 0.f;
#pragma unroll
            for (int fn = 0; fn < 4; fn++) {
                int go = w * 64 + fn * 16 + l15;
                float vv = fmaxf(acc[fm][fn][rg] + bb[fn], 0.f);
                orow[go] = vv;
                tile[i * 256 + go] = vv;
                s2 += vv * vv;
            }
            s2 += __shfl_xor(s2, 1);
            s2 += __shfl_xor(s2, 2);
            s2 += __shfl_xor(s2, 4);
            s2 += __shfl_xor(s2, 8);
            if (l15 == 0) atomicAdd(&ssq[i], s2);
        }
    __syncthreads();
    if (tid < 32) ssq[tid] = 1.f / (sqrtf(ssq[tid]) + 1e-8f);
    __syncthreads();
#pragma unroll
    for (int it = 0; it < 4; it++) {
        int f = tid + it * 256;                  // 0..1023 chunk ids
        int row = f >> 5, c = f & 31;
        float4 xa = *(const float4*)&tile[row * 256 + c * 8];
        float4 xb = *(const float4*)&tile[row * 256 + c * 8 + 4];
        float iv = ssq[row];
        us8 o = {f2bf(xa.x * iv), f2bf(xa.y * iv), f2bf(xa.z * iv), f2bf(xa.w * iv),
                 f2bf(xb.x * iv), f2bf(xb.y * iv), f2bf(xb.z * iv), f2bf(xb.w * iv)};
        int rx = d * 64 + half * 32 + row;       // rx&7 == row&7 (32 % 8 == 0)
        int slot = (c & 24) | ((c & 7) ^ (row & 7));
        *(us8*)&xnb[((size_t)mod * NROW + rx) * GDIM + slot * 8] = o;
    }
}

// ---- K9: bf16 MFMA sim. 128x128 tiles, 4 waves, 32 KiB LDS.
//      R6 LESSON: pointer arrays + tight launch_bounds -> scratch spills.
//      NAMED scalar pointers + (256,4). K-step in GLOBAL POINTER, builtin
//      offset 0 (R5 LESSON: offset arg moves the LDS DESTINATION).
//      exp2-folded epilogue; diag confined to ci==cj blocks. ----
#define TILE9 128
#define STAGE9(ELT)                                                        \
    {                                                                      \
        __builtin_amdgcn_global_load_lds(pa0 + (ELT), la0, 16, 0, 0);      \
        __builtin_amdgcn_global_load_lds(pb0 + (ELT), lb0, 16, 0, 0);      \
        __builtin_amdgcn_global_load_lds(pa1 + (ELT), la1, 16, 0, 0);      \
        __builtin_amdgcn_global_load_lds(pb1 + (ELT), lb1, 16, 0, 0);      \
        __builtin_amdgcn_global_load_lds(pa2 + (ELT), la2, 16, 0, 0);      \
        __builtin_amdgcn_global_load_lds(pb2 + (ELT), lb2, 16, 0, 0);      \
        __builtin_amdgcn_global_load_lds(pa3 + (ELT), la3, 16, 0, 0);      \
        __builtin_amdgcn_global_load_lds(pb3 + (ELT), lb3, 16, 0, 0);      \
    }
__global__ __launch_bounds__(256, 4) void k9_mfma(const ushort* __restrict__ xnb,
                                                  float* __restrict__ rs,
                                                  float* __restrict__ cs,
                                                  float* __restrict__ diag) {
    // grid = 32 x 32 x 3 = 3072 blocks; 3072 % 8 == 0 -> simple bijection
    int lin = blockIdx.x + (blockIdx.y << 5) + (blockIdx.z << 10);
    int vid = (lin >> 3) + (lin & 7) * 384;      // XCD-contiguous remap
    int p  = vid >> 10;
    int r0 = vid & 1023;
    int ci = r0 >> 5, cj = r0 & 31;
    int px = (p == 2) ? 1 : 0;
    int py = (p == 0) ? 1 : 2;
    const ushort* A = xnb + ((size_t)px * NROW + ci * TILE9) * GDIM;
    const ushort* B = xnb + ((size_t)py * NROW + cj * TILE9) * GDIM;

    __shared__ __align__(16) ushort As[TILE9 * 64];   // 16 KiB
    __shared__ __align__(16) ushort Bs[TILE9 * 64];   // 16 KiB

    const int tid = threadIdx.x;
    const int lane = tid & 63, w = tid >> 6;     // 4 waves
    const int wrow = w >> 1, wcol = w & 1;       // 2 x 2 wave grid
    const int qd = lane >> 4, l15 = lane & 15;
    const int lrow = lane >> 3, lslot = lane & 7;

    // hoisted staging base addresses as NAMED scalars (no arrays -> no spill)
    const int rbase = w * 32 + lrow;
    const int cbase = lslot * 8;
    const gm_us* pa0 = (gm_us*)(A + (size_t)(rbase +  0) * GDIM + cbase);
    const gm_us* pa1 = (gm_us*)(A + (size_t)(rbase +  8) * GDIM + cbase);
    const gm_us* pa2 = (gm_us*)(A + (size_t)(rbase + 16) * GDIM + cbase);
    const gm_us* pa3 = (gm_us*)(A + (size_t)(rbase + 24) * GDIM + cbase);
    const gm_us* pb0 = (gm_us*)(B + (size_t)(rbase +  0) * GDIM + cbase);
    const gm_us* pb1 = (gm_us*)(B + (size_t)(rbase +  8) * GDIM + cbase);
    const gm_us* pb2 = (gm_us*)(B + (size_t)(rbase + 16) * GDIM + cbase);
    const gm_us* pb3 = (gm_us*)(B + (size_t)(rbase + 24) * GDIM + cbase);
    lds_us* la0 = (lds_us*)&As[(w * 32 +  0) * 64];
    lds_us* la1 = (lds_us*)&As[(w * 32 +  8) * 64];
    lds_us* la2 = (lds_us*)&As[(w * 32 + 16) * 64];
    lds_us* la3 = (lds_us*)&As[(w * 32 + 24) * 64];
    lds_us* lb0 = (lds_us*)&Bs[(w * 32 +  0) * 64];
    lds_us* lb1 = (lds_us*)&Bs[(w * 32 +  8) * 64];
    lds_us* lb2 = (lds_us*)&Bs[(w * 32 + 16) * 64];
    lds_us* lb3 = (lds_us*)&Bs[(w * 32 + 24) * 64];

    f32x4 acc[4][4] = {};

    auto compute = [&]() {
#pragma unroll
        for (int kk = 0; kk < 2; kk++) {
            bf16x8 af[4], bfv[4];
#pragma unroll
            for (int fm = 0; fm < 4; fm++) {
                int ar = wrow * 64 + fm * 16 + l15;
                af[fm] = *(const bf16x8*)&As[ar * 64 + ((kk * 4 + qd) ^ (ar & 7)) * 8];
            }
#pragma unroll
            for (int fn = 0; fn < 4; fn++) {
                int br = wcol * 64 + fn * 16 + l15;
                bfv[fn] = *(const bf16x8*)&Bs[br * 64 + ((kk * 4 + qd) ^ (br & 7)) * 8];
            }
#pragma unroll
            for (int fm = 0; fm < 4; fm++)
#pragma unroll
                for (int fn = 0; fn < 4; fn++)
                    acc[fm][fn] = __builtin_amdgcn_mfma_f32_16x16x32_bf16(
                        af[fm], bfv[fn], acc[fm][fn], 0, 0, 0);
        }
    };

    STAGE9(0);   __syncthreads(); compute(); __syncthreads();
    STAGE9(64);  __syncthreads(); compute(); __syncthreads();
    STAGE9(128); __syncthreads(); compute(); __syncthreads();
    STAGE9(192); __syncthreads(); compute(); __syncthreads();

    // epilogue: exp2(acc * INV_TAU*log2e), packed f32x4 accumulation
    const float C2 = INV_TAU * 1.44269504088896f;
    f32x4 rv[4] = {};                            // row partials, [fm][rg]
    f32x4 cv[4] = {};                            // col partials, [fn][rg-folded]
#pragma unroll
    for (int fm = 0; fm < 4; fm++)
#pragma unroll
        for (int fn = 0; fn < 4; fn++) {
            f32x4 sv = acc[fm][fn] * C2;         // v_pk_mul_f32 x2
            f32x4 ev;
#pragma unroll
            for (int rg = 0; rg < 4; rg++)
                ev[rg] = exp2f(sv[rg]);          // v_exp_f32
            rv[fm] += ev;                        // v_pk_add_f32 x2
            cv[fn] += ev;                        // v_pk_add_f32 x2
        }
    if (ci == cj) {                              // only 1/32 blocks hold diag
#pragma unroll
        for (int fm = 0; fm < 4; fm++)
#pragma unroll
            for (int fn = 0; fn < 4; fn++)
#pragma unroll
                for (int rg = 0; rg < 4; rg++) {
                    int lr = wrow * 64 + fm * 16 + qd * 4 + rg;
                    int lc = wcol * 64 + fn * 16 + l15;
                    if (lr == lc)
                        diag[p * NROW + ci * TILE9 + lr] = acc[fm][fn][rg] * INV_TAU;
                }
    }
#pragma unroll
    for (int fm = 0; fm < 4; fm++)
#pragma unroll
        for (int rg = 0; rg < 4; rg++) {
            float s = rv[fm][rg];
            s += __shfl_xor(s, 1);
            s += __shfl_xor(s, 2);
            s += __shfl_xor(s, 4);
            s += __shfl_xor(s, 8);
            if (l15 == 0)
                atomicAdd(&rs[p * NROW + ci * TILE9 + wrow * 64 + fm * 16 + qd * 4 + rg], s);
        }
#pragma unroll
    for (int fn = 0; fn < 4; fn++) {
        float s = (cv[fn][0] + cv[fn][1]) + (cv[fn][2] + cv[fn][3]);
        s += __shfl_xor(s, 16);
        s += __shfl_xor(s, 32);
        if (qd == 0)
            atomicAdd(&cs[p * NROW + cj * TILE9 + wcol * 64 + fn * 16 + l15], s);
    }
}

// ---- K10: final loss reduction ----
__global__ void k10_loss(const float* __restrict__ diag, const float* __restrict__ rs,
                         const float* __restrict__ cs, float* __restrict__ outp) {
    float acc = 0.f;
    for (int i = threadIdx.x; i < 3 * NROW; i += 256)
        acc += 2.f * diag[i] - logf(rs[i]) - logf(cs[i]);
    int lane = threadIdx.x & 63, wv = threadIdx.x >> 6;
    for (int o = 32; o; o >>= 1) acc += __shfl_down(acc, o);
    __shared__ float red[4];
    if (lane == 0) red[wv] = acc;
    __syncthreads();
    if (threadIdx.x == 0) {
        float tot = red[0] + red[1] + red[2] + red[3];
        outp[(size_t)NROW * 768] = -tot / (NROW * 6.0f);
    }
}

extern "C" void kernel_launch(void* const* d_in, const int* in_sizes, int n_in,
                              void* d_out, int out_size, void* d_ws, size_t ws_size,
                              hipStream_t stream) {
    const float* t   = (const float*)d_in[0];
    const float* a   = (const float*)d_in[1];
    const float* v   = (const float*)d_in[2];
    const float* Wfc = (const float*)d_in[3];
    const float* bfc = (const float*)d_in[4];
    const float* Wh  = (const float*)d_in[5];
    const float* bh  = (const float*)d_in[6];
    float* outp = (float*)d_out;
    float* ws = (float*)d_ws;

    // workspace layout (floats); all offsets 16B-aligned
    float* sq    = ws;                       // 12288
    float* d2    = sq + 12288;               // 2359296 (holds 2*dot; dead after k2 -> xnb)
    float* HbF   = d2 + 2359296;             // 1179648 (fp16 Hb 12288x192)
    float* HbTF  = HbF + 1179648;            // 1179648
    float* degE  = HbTF + 1179648;           // 12288
    float* degV  = degE + 12288;             // 12288
    float* featF = degV + 12288;             // 3145728 (unused now)
    float* WfcTF = featF + 3145728;          // 65536   (fp16 256x512)
    float* WhTF  = WfcTF + 65536;            // 32768   (fp16 256x256)
    float* XTF   = WhTF + 32768;             // 1572864 (unused now)
    float* ETF   = XTF + 1572864;            // 1572864
    float* YF    = ETF + 1572864;            // 1572864 (unused now)
    float* rs    = YF + 1572864;             // 12288
    float* cs    = rs + 12288;               // 12288
    float* diag  = cs + 12288;               // 12288

    _Float16* Hb    = (_Float16*)HbF;
    _Float16* HbT   = (_Float16*)HbTF;
    _Float16* WfcT  = (_Float16*)WfcTF;
    _Float16* WhT   = (_Float16*)WhTF;
    _Float16* ET    = (_Float16*)ETF;
    ushort*   xnb   = (ushort*)d2;           // bf16[3][4096][256] (swizzled)

    kA     <<<7920, 256, 0, stream>>>(t, a, v, Wfc, Wh, WfcT, WhT,
                                      sq, rs, cs, degV, HbT, d2);
    k2_topk<<<3072, 256, 0, stream>>>(d2, sq, Hb, HbT, degE, degV);
    k34_XE <<<dim3(8, 64), 192, 0, stream>>>(WfcT, t, a, v, bfc, Hb, degE, ET);
    k56_Yout<<<dim3(6, 64), 256, 0, stream>>>(HbT, ET, degV, WhT, bh, outp, xnb);
    k9_mfma<<<dim3(32, 32, 3), 256, 0, stream>>>(xnb, rs, cs, diag);
    k10_loss<<<1, 256, 0, stream>>>(diag, rs, cs, outp);
}